// Round 9
// baseline (319.755 us; speedup 1.0000x reference)
//
#include <hip/hip_runtime.h>
#include <hip/hip_bf16.h>

// CDC conv: out = conv3x3(x,W,zero-pad) + b - 0.7 * laplacian(channel_sum(x), edge-pad)
// bf16 MFMA implicit GEMM (9 tap-GEMMs, K=Cin), fp32 stencil epilogue.
// Round 9: combine R4 (3 waves/SIMD) + R6 (W broadcast). Block = 256thr/4 waves,
// tile 128co x 128w x 1h -> 3 input rows = 48KB LDS -> 3 blocks/CU (3/SIMD).
// Wave = 64co x 64pix, acc[4][4] = 64 AGPR; (256,3) budget ~170 >= ~154 demand
// (R4 precedent, no spill; R5/R7/R8 lesson: 4 waves/SIMD always spills here).
// ws layout: [0,128MB) x_t bf16 [b][h][w][ci] (chunk-swizzled),
// [128MB,+288KB) W_packed [tap][kchunk:16][co:128][8ci] bf16 (linear),
// then s[b][h][w] f32 (8MB).

typedef __attribute__((ext_vector_type(8))) short short8;
typedef __attribute__((ext_vector_type(4))) float f32x4;

#define THETA 0.7f
#define XT_OFF   0
#define WP_OFF   134217728ull          // 32*128*128*128*2
#define S_OFF    (134217728ull + 294912ull)

__device__ __forceinline__ unsigned short f2b(float f) {
  unsigned u = __builtin_bit_cast(unsigned, f);
  u += 0x7FFFu + ((u >> 16) & 1u);     // RNE
  return (unsigned short)(u >> 16);
}

__device__ __forceinline__ void gload_lds16(const void* g, void* l) {
  __builtin_amdgcn_global_load_lds(
      (const __attribute__((address_space(1))) unsigned int*)g,
      (__attribute__((address_space(3))) unsigned int*)l, 16, 0, 0);
}

// ---- pack W[co][ci][3][3] f32 -> wp[tap][c:16][co:128][8] bf16 (linear)
__global__ void pack_w_kernel(const float* __restrict__ w, char* __restrict__ wp) {
  const int co = blockIdx.x, ci = threadIdx.x;
  const float* src = w + ((size_t)co * 128 + ci) * 9;
  const int c = ci >> 3, j = ci & 7;
  #pragma unroll
  for (int tap = 0; tap < 9; ++tap) {
    const unsigned short bv = f2b(src[tap]);
    *(unsigned short*)(wp + (((size_t)(tap * 16 + c) * 128 + co) * 16 + j * 2)) = bv;
  }
}

// ---- x[b][ci][h][w] f32 -> x_t[b][h][w][ci] bf16 (swizzled) + s[b][h][w] = sum_ci x
__global__ __launch_bounds__(256)
void transpose_sum_kernel(const float* __restrict__ x, char* __restrict__ xt,
                          float* __restrict__ s) {
  __shared__ float tile[128][129];
  __shared__ float s2[2][128];
  const int h = blockIdx.x, b = blockIdx.y;
  const int t = threadIdx.x;
  {
    const int ciq = t >> 5;              // 0..7
    const int wq = (t & 31) << 2;        // 0..124
    #pragma unroll
    for (int i = 0; i < 16; ++i) {
      const int ci = i * 8 + ciq;
      const float4 v = *(const float4*)(x + (((size_t)(b * 128 + ci) * 128 + h) * 128 + wq));
      tile[ci][wq] = v.x; tile[ci][wq + 1] = v.y;
      tile[ci][wq + 2] = v.z; tile[ci][wq + 3] = v.w;
    }
  }
  __syncthreads();
  {
    const int w = t & 127, p = t >> 7;
    float acc = 0.f;
    #pragma unroll 8
    for (int j = 0; j < 64; ++j) acc += tile[p * 64 + j][w];
    s2[p][w] = acc;
  }
  char* rowb = xt + (size_t)(b * 128 + h) * 32768;
  // 128 w * 16 chunks(16B) = 2048 chunks; 256 threads -> 8 iters
  #pragma unroll
  for (int i = 0; i < 8; ++i) {
    const int u = i * 256 + t;           // 0..2047 chunk id
    const int w = u >> 4, chunk = u & 15;
    const int ci0 = chunk * 8;
    short8 o;
    #pragma unroll
    for (int j = 0; j < 8; ++j) o[j] = (short)f2b(tile[ci0 + j][w]);
    *(short8*)(rowb + w * 256 + ((chunk ^ (w & 7)) * 16)) = o;
  }
  __syncthreads();
  if (t < 128) s[(size_t)(b * 128 + h) * 128 + t] = s2[0][t] + s2[1][t];
}

// ---- conv: 4 waves; block tile = 128co x 128w x 1h; 3 input rows in LDS
__global__ __launch_bounds__(256, 3)
void conv_mfma_kernel(const char* __restrict__ xt, const char* __restrict__ wp,
                      const float* __restrict__ bias, const float* __restrict__ s,
                      float* __restrict__ out) {
  __shared__ uint4 xs4[3 * 1024];   // 48KB: 3 input rows * 128w * 64ci bf16
  char* xs = (char*)xs4;

  // bijective XCD swizzle: 4096 blocks, 8 XCDs, 512 contiguous per XCD.
  // adjacent h on one XCD share 2/3 input rows -> L2 hits.
  const int bid = blockIdx.x;
  const int sw = (bid & 7) * 512 + (bid >> 3);
  const int h = sw & 127;
  const int b = sw >> 7;

  const int t = threadIdx.x;
  const int lane = t & 63, wave = t >> 6;
  const int wm = wave >> 1, wn = wave & 1;
  const int l15 = lane & 15, lg = lane >> 4;

  f32x4 acc[4][4];
  #pragma unroll
  for (int m = 0; m < 4; ++m)
    #pragma unroll
    for (int n = 0; n < 4; ++n)
      acc[m][n] = (f32x4){0.f, 0.f, 0.f, 0.f};

  auto stage_x = [&](int cih) {
    #pragma unroll
    for (int r = 0; r < 3; ++r) {  // input rows h-1 .. h+1, zero-pad OOB
      const int hh = h - 1 + r;
      if ((unsigned)hh < 128u) {
        const char* rb = xt + ((size_t)(b * 128 + hh) * 32768 + cih * 128);
        #pragma unroll
        for (int i = 0; i < 4; ++i) {
          const int u = i * 256 + t;   // 0..1023: 16KB row-half
          gload_lds16(rb + (size_t)(u >> 3) * 256 + (u & 7) * 16,
                      xs + r * 16384 + u * 16);
        }
      } else {
        #pragma unroll
        for (int i = 0; i < 4; ++i) {
          const int u = i * 256 + t;
          *(uint4*)(xs + r * 16384 + u * 16) = make_uint4(0u, 0u, 0u, 0u);
        }
      }
    }
  };

  auto compute_half = [&](int khalf) {
    #pragma unroll
    for (int kh = 0; kh < 3; ++kh) {
      const char* xrow = xs + kh * 16384;  // input row h-1+kh
      #pragma unroll
      for (int dxi = 0; dxi < 3; ++dxi) {
        const int tap = kh * 3 + dxi;
        const int dx = dxi - 1;
        // A-fragments: 2 variants per block (wm) -> L1 broadcast
        const char* wb = wp + (size_t)(tap * 16 + khalf * 8) * 2048;
        short8 af[2][4];
        #pragma unroll
        for (int kk = 0; kk < 2; ++kk)
          #pragma unroll
          for (int m = 0; m < 4; ++m)
            af[kk][m] = *(const short8*)(wb + (kk * 4 + lg) * 2048 +
                                         (wm * 64 + m * 16 + l15) * 16);
        #pragma unroll
        for (int kk = 0; kk < 2; ++kk) {
          short8 bf[4];
          #pragma unroll
          for (int n = 0; n < 4; ++n) {
            const int wsrc = wn * 64 + n * 16 + l15 + dx;
            short8 v = {0, 0, 0, 0, 0, 0, 0, 0};
            if ((unsigned)wsrc < 128u) {
              const int phys = (kk * 4 + lg) ^ (wsrc & 7);
              v = *(const short8*)(xrow + wsrc * 128 + phys * 16);
            }
            bf[n] = v;
          }
          #pragma unroll
          for (int m = 0; m < 4; ++m)
            #pragma unroll
            for (int n = 0; n < 4; ++n)
              acc[m][n] = __builtin_amdgcn_mfma_f32_16x16x32_bf16(af[kk][m], bf[n], acc[m][n], 0, 0, 0);
        }
      }
    }
  };

  stage_x(0);
  __syncthreads();                 // xs half-0 ready
  compute_half(0);
  __syncthreads();                 // all waves done reading xs half-0
  stage_x(1);
  __syncthreads();                 // xs half-1 ready
  compute_half(1);

  // epilogue: per-thread fp32 stencil from s (L3-resident) + bias (L2)
  const float* sb = s + (size_t)b * 16384;
  float dif[4];
  #pragma unroll
  for (int n = 0; n < 4; ++n) {
    const int w = wn * 64 + n * 16 + l15;
    const float sc = sb[h * 128 + w];
    const float up = sb[(h > 0 ? h - 1 : 0) * 128 + w];
    const float dn = sb[(h < 127 ? h + 1 : 127) * 128 + w];
    const float lf = sb[h * 128 + (w > 0 ? w - 1 : 0)];
    const float rt = sb[h * 128 + (w < 127 ? w + 1 : 127)];
    dif[n] = up + dn + lf + rt - 4.0f * sc;
  }
  // C/D layout (verified m89): col=lane&15 (=pix), row=(lane>>4)*4+reg (=co)
  #pragma unroll
  for (int m = 0; m < 4; ++m) {
    #pragma unroll
    for (int r = 0; r < 4; ++r) {
      const int co = wm * 64 + m * 16 + lg * 4 + r;
      const float bv = bias[co];
      float* orow = out + ((size_t)(b * 128 + co) * 128 + h) * 128;
      #pragma unroll
      for (int n = 0; n < 4; ++n) {
        const int w = wn * 64 + n * 16 + l15;
        orow[w] = acc[m][n][r] + bv - THETA * dif[n];
      }
    }
  }
}

extern "C" void kernel_launch(void* const* d_in, const int* in_sizes, int n_in,
                              void* d_out, int out_size, void* d_ws, size_t ws_size,
                              hipStream_t stream) {
  const float* x = (const float*)d_in[0];
  const float* W = (const float*)d_in[1];
  const float* bias = (const float*)d_in[2];
  float* out = (float*)d_out;
  char* ws = (char*)d_ws;
  char* xt = ws + XT_OFF;
  char* wp = ws + WP_OFF;
  float* s = (float*)(ws + S_OFF);
  // needs ~142,901,248 bytes of ws
  pack_w_kernel<<<dim3(128), dim3(128), 0, stream>>>(W, wp);
  transpose_sum_kernel<<<dim3(128, 32), dim3(256), 0, stream>>>(x, xt, s);
  conv_mfma_kernel<<<dim3(4096), dim3(256), 0, stream>>>(xt, wp, bias, s, out);
}

// Round 10
// 272.318 us; speedup vs baseline: 1.1742x; 1.1742x over previous
//
#include <hip/hip_runtime.h>
#include <hip/hip_bf16.h>

// CDC conv: out = conv3x3(x,W,zero-pad) + b - 0.7 * laplacian(channel_sum(x), edge-pad)
// bf16 MFMA implicit GEMM (9 tap-GEMMs, K=Cin), fp32 stencil epilogue.
// Round 10: switch to mfma_f32_32x32x16_bf16. Same 64co x 64pix wave tile as
// 16x16 version but acc = 2x2 f32x16 (64 AGPR), per-ks operands af[2]+bf[2]
// = 16 VGPR (vs 48), half the MFMA/ds_read/W-load instructions. Demand ~120
// regs -> fits (256,3) budget ~168 spill-free -> 3 waves/SIMD (R4..R9 lesson:
// every earlier 3-4 wave config spilled; spill = +40..260MB WRITE_SIZE).
// Block = 256thr/4 waves (wm x wn), tile 128co x 128w x 1h; 3 input rows in
// LDS (48KB, 3 blocks/CU); W block-broadcast from L1/L2 (R6 lesson).
// ws layout: [0,128MB) x_t bf16 [b][h][w][ci] (chunk-swizzled),
// [128MB,+288KB) W_packed [tap][ks:8][kb:2][co:128][8ci] bf16,
// then s[b][h][w] f32 (8MB).

typedef __attribute__((ext_vector_type(8))) short short8;
typedef __attribute__((ext_vector_type(16))) float f32x16;

#define THETA 0.7f
#define XT_OFF   0
#define WP_OFF   134217728ull          // 32*128*128*128*2
#define S_OFF    (134217728ull + 294912ull)

__device__ __forceinline__ unsigned short f2b(float f) {
  unsigned u = __builtin_bit_cast(unsigned, f);
  u += 0x7FFFu + ((u >> 16) & 1u);     // RNE
  return (unsigned short)(u >> 16);
}

__device__ __forceinline__ void gload_lds16(const void* g, void* l) {
  __builtin_amdgcn_global_load_lds(
      (const __attribute__((address_space(1))) unsigned int*)g,
      (__attribute__((address_space(3))) unsigned int*)l, 16, 0, 0);
}

// ---- pack W[co][ci][3][3] f32 -> wp[tap][ks:8][kb:2][co:128][8] bf16
// k = ci: ks = ci>>4 (k-step of 16), kb = (ci>>3)&1 (lane half), j = ci&7
__global__ void pack_w_kernel(const float* __restrict__ w, char* __restrict__ wp) {
  const int co = blockIdx.x, ci = threadIdx.x;
  const float* src = w + ((size_t)co * 128 + ci) * 9;
  const int ks = ci >> 4, kb = (ci >> 3) & 1, j = ci & 7;
  #pragma unroll
  for (int tap = 0; tap < 9; ++tap) {
    const unsigned short bv = f2b(src[tap]);
    *(unsigned short*)(wp + ((size_t)((tap * 8 + ks) * 2 + kb) * 2048 + co * 16 + j * 2)) = bv;
  }
}

// ---- x[b][ci][h][w] f32 -> x_t[b][h][w][ci] bf16 (swizzled) + s[b][h][w] = sum_ci x
__global__ __launch_bounds__(256)
void transpose_sum_kernel(const float* __restrict__ x, char* __restrict__ xt,
                          float* __restrict__ s) {
  __shared__ float tile[128][129];
  __shared__ float s2[2][128];
  const int h = blockIdx.x, b = blockIdx.y;
  const int t = threadIdx.x;
  {
    const int ciq = t >> 5;              // 0..7
    const int wq = (t & 31) << 2;        // 0..124
    #pragma unroll
    for (int i = 0; i < 16; ++i) {
      const int ci = i * 8 + ciq;
      const float4 v = *(const float4*)(x + (((size_t)(b * 128 + ci) * 128 + h) * 128 + wq));
      tile[ci][wq] = v.x; tile[ci][wq + 1] = v.y;
      tile[ci][wq + 2] = v.z; tile[ci][wq + 3] = v.w;
    }
  }
  __syncthreads();
  {
    const int w = t & 127, p = t >> 7;
    float acc = 0.f;
    #pragma unroll 8
    for (int j = 0; j < 64; ++j) acc += tile[p * 64 + j][w];
    s2[p][w] = acc;
  }
  char* rowb = xt + (size_t)(b * 128 + h) * 32768;
  // 128 w * 16 chunks(16B) = 2048 chunks; 256 threads -> 8 iters
  #pragma unroll
  for (int i = 0; i < 8; ++i) {
    const int u = i * 256 + t;           // 0..2047 chunk id
    const int w = u >> 4, chunk = u & 15;
    const int ci0 = chunk * 8;
    short8 o;
    #pragma unroll
    for (int j = 0; j < 8; ++j) o[j] = (short)f2b(tile[ci0 + j][w]);
    *(short8*)(rowb + w * 256 + ((chunk ^ (w & 7)) * 16)) = o;
  }
  __syncthreads();
  if (t < 128) s[(size_t)(b * 128 + h) * 128 + t] = s2[0][t] + s2[1][t];
}

// ---- conv: 4 waves; block 128co x 128w x 1h; 32x32x16 MFMA; 3 rows in LDS
__global__ __launch_bounds__(256, 3)
void conv_mfma_kernel(const char* __restrict__ xt, const char* __restrict__ wp,
                      const float* __restrict__ bias, const float* __restrict__ s,
                      float* __restrict__ out) {
  __shared__ uint4 xs4[3 * 1024];   // 48KB: 3 input rows * 128w * 64ci bf16
  char* xs = (char*)xs4;

  // bijective XCD swizzle: 4096 blocks, 8 XCDs, 512 contiguous per XCD.
  const int bid = blockIdx.x;
  const int sw = (bid & 7) * 512 + (bid >> 3);
  const int h = sw & 127;
  const int b = sw >> 7;

  const int t = threadIdx.x;
  const int lane = t & 63, wave = t >> 6;
  const int wm = wave >> 1, wn = wave & 1;
  const int l31 = lane & 31, kb = lane >> 5;

  f32x16 acc[2][2];
  #pragma unroll
  for (int mt = 0; mt < 2; ++mt)
    #pragma unroll
    for (int nt = 0; nt < 2; ++nt)
      #pragma unroll
      for (int r = 0; r < 16; ++r)
        acc[mt][nt][r] = 0.f;

  auto stage_x = [&](int cih) {
    #pragma unroll
    for (int r = 0; r < 3; ++r) {  // input rows h-1 .. h+1, zero-pad OOB
      const int hh = h - 1 + r;
      if ((unsigned)hh < 128u) {
        const char* rb = xt + ((size_t)(b * 128 + hh) * 32768 + cih * 128);
        #pragma unroll
        for (int i = 0; i < 4; ++i) {
          const int u = i * 256 + t;   // 0..1023: 16KB row-half
          gload_lds16(rb + (size_t)(u >> 3) * 256 + (u & 7) * 16,
                      xs + r * 16384 + u * 16);
        }
      } else {
        #pragma unroll
        for (int i = 0; i < 4; ++i) {
          const int u = i * 256 + t;
          *(uint4*)(xs + r * 16384 + u * 16) = make_uint4(0u, 0u, 0u, 0u);
        }
      }
    }
  };

  auto compute_half = [&](int cih) {
    #pragma unroll
    for (int kh = 0; kh < 3; ++kh) {
      const char* xrow = xs + kh * 16384;  // input row h-1+kh
      #pragma unroll
      for (int dxi = 0; dxi < 3; ++dxi) {
        const int tap = kh * 3 + dxi;
        const int dx = dxi - 1;
        // W base for this tap + ci-half; layout [tap][ks][kb][co][16B]
        const char* wb = wp + (size_t)((tap * 8 + cih * 4) * 2) * 2048;
        #pragma unroll
        for (int ks = 0; ks < 4; ++ks) {      // 4 k-steps of 16 per ci-half
          // A-fragments: 2 variants/block (wm) -> L1 broadcast.
          // A layout: row=l&31, k=(l>>5)*8+j
          short8 af[2];
          #pragma unroll
          for (int mt = 0; mt < 2; ++mt)
            af[mt] = *(const short8*)(wb + (ks * 2 + kb) * 2048 +
                                      (wm * 64 + mt * 32 + l31) * 16);
          // B-fragments from LDS: col(w)=l&31 (+dx), k-chunk = ks*2+kb
          short8 bf[2];
          #pragma unroll
          for (int nt = 0; nt < 2; ++nt) {
            const int wsrc = wn * 64 + nt * 32 + l31 + dx;
            short8 v = {0, 0, 0, 0, 0, 0, 0, 0};
            if ((unsigned)wsrc < 128u) {
              const int phys = (ks * 2 + kb) ^ (wsrc & 7);
              v = *(const short8*)(xrow + wsrc * 128 + phys * 16);
            }
            bf[nt] = v;
          }
          #pragma unroll
          for (int mt = 0; mt < 2; ++mt)
            #pragma unroll
            for (int nt = 0; nt < 2; ++nt)
              acc[mt][nt] = __builtin_amdgcn_mfma_f32_32x32x16_bf16(
                  af[mt], bf[nt], acc[mt][nt], 0, 0, 0);
        }
      }
    }
  };

  stage_x(0);
  __syncthreads();                 // xs half-0 ready
  compute_half(0);
  __syncthreads();                 // all waves done reading xs half-0
  stage_x(1);
  __syncthreads();                 // xs half-1 ready
  compute_half(1);

  // epilogue: per-thread fp32 stencil from s (L3-resident) + bias (L2)
  const float* sb = s + (size_t)b * 16384;
  float dif[2];
  #pragma unroll
  for (int nt = 0; nt < 2; ++nt) {
    const int w = wn * 64 + nt * 32 + l31;
    const float sc = sb[h * 128 + w];
    const float up = sb[(h > 0 ? h - 1 : 0) * 128 + w];
    const float dn = sb[(h < 127 ? h + 1 : 127) * 128 + w];
    const float lf = sb[h * 128 + (w > 0 ? w - 1 : 0)];
    const float rt = sb[h * 128 + (w < 127 ? w + 1 : 127)];
    dif[nt] = up + dn + lf + rt - 4.0f * sc;
  }
  // 32x32 C/D layout (verified m74/m101): col=lane&31, row=(r&3)+8*(r>>2)+4*(lane>>5)
  #pragma unroll
  for (int mt = 0; mt < 2; ++mt) {
    #pragma unroll
    for (int r = 0; r < 16; ++r) {
      const int co = wm * 64 + mt * 32 + (r & 3) + 8 * (r >> 2) + 4 * kb;
      const float bv = bias[co];
      float* orow = out + ((size_t)(b * 128 + co) * 128 + h) * 128;
      #pragma unroll
      for (int nt = 0; nt < 2; ++nt) {
        const int w = wn * 64 + nt * 32 + l31;
        orow[w] = acc[mt][nt][r] + bv - THETA * dif[nt];
      }
    }
  }
}

extern "C" void kernel_launch(void* const* d_in, const int* in_sizes, int n_in,
                              void* d_out, int out_size, void* d_ws, size_t ws_size,
                              hipStream_t stream) {
  const float* x = (const float*)d_in[0];
  const float* W = (const float*)d_in[1];
  const float* bias = (const float*)d_in[2];
  float* out = (float*)d_out;
  char* ws = (char*)d_ws;
  char* xt = ws + XT_OFF;
  char* wp = ws + WP_OFF;
  float* s = (float*)(ws + S_OFF);
  // needs ~142,901,248 bytes of ws
  pack_w_kernel<<<dim3(128), dim3(128), 0, stream>>>(W, wp);
  transpose_sum_kernel<<<dim3(128, 32), dim3(256), 0, stream>>>(x, xt, s);
  conv_mfma_kernel<<<dim3(4096), dim3(256), 0, stream>>>(xt, wp, bias, s, out);
}

// Round 11
// 270.685 us; speedup vs baseline: 1.1813x; 1.0060x over previous
//
#include <hip/hip_runtime.h>
#include <hip/hip_bf16.h>

// CDC conv: out = conv3x3(x,W,zero-pad) + b - 0.7 * laplacian(channel_sum(x), edge-pad)
// bf16 MFMA implicit GEMM (9 tap-GEMMs, K=Cin), fp32 stencil epilogue.
// Round 11: kill the 4-way LDS conflict of R10 by TRANSPOSING xt to ci-major:
// xt[b][h][cih][q:8][w:128][16B]. B-read becomes stride-1 across lanes
// (conflict-free), swizzle logic deleted, stage_x is a pure linear copy.
// (R10 lesson: 32-row b128 reads of a [w][ci] row-major tile are 4-way
// conflicted by pigeonhole; no 3-bit XOR can fix it.)
// Keep R10: 32x32x16 MFMA, block 128co x 128w x 1h, 4 waves, (256,3), 48KB,
// W block-broadcast [tap][ks:8][kb:2][co:128][8ci] (spill-free, WRITE=262144).
// ws: [0,128MB) x_t, [128MB,+288KB) W_packed, then s[b][h][w] f32 (8MB).

typedef __attribute__((ext_vector_type(8))) short short8;
typedef __attribute__((ext_vector_type(16))) float f32x16;

#define THETA 0.7f
#define XT_OFF   0
#define WP_OFF   134217728ull          // 32*128*128*128*2
#define S_OFF    (134217728ull + 294912ull)

__device__ __forceinline__ unsigned short f2b(float f) {
  unsigned u = __builtin_bit_cast(unsigned, f);
  u += 0x7FFFu + ((u >> 16) & 1u);     // RNE
  return (unsigned short)(u >> 16);
}

__device__ __forceinline__ void gload_lds16(const void* g, void* l) {
  __builtin_amdgcn_global_load_lds(
      (const __attribute__((address_space(1))) unsigned int*)g,
      (__attribute__((address_space(3))) unsigned int*)l, 16, 0, 0);
}

// ---- pack W[co][ci][3][3] f32 -> wp[tap][ks:8][kb:2][co:128][8] bf16
// k = ci: ks = ci>>4 (k-step of 16), kb = (ci>>3)&1 (lane half), j = ci&7
__global__ void pack_w_kernel(const float* __restrict__ w, char* __restrict__ wp) {
  const int co = blockIdx.x, ci = threadIdx.x;
  const float* src = w + ((size_t)co * 128 + ci) * 9;
  const int ks = ci >> 4, kb = (ci >> 3) & 1, j = ci & 7;
  #pragma unroll
  for (int tap = 0; tap < 9; ++tap) {
    const unsigned short bv = f2b(src[tap]);
    *(unsigned short*)(wp + ((size_t)((tap * 8 + ks) * 2 + kb) * 2048 + co * 16 + j * 2)) = bv;
  }
}

// ---- x[b][ci][h][w] f32 -> x_t[b][h][cih:2][q:8][w:128][16B] bf16 (ci-major)
//      + s[b][h][w] = sum_ci x
__global__ __launch_bounds__(256)
void transpose_sum_kernel(const float* __restrict__ x, char* __restrict__ xt,
                          float* __restrict__ s) {
  __shared__ float tile[128][129];
  __shared__ float s2[2][128];
  const int h = blockIdx.x, b = blockIdx.y;
  const int t = threadIdx.x;
  {
    const int ciq = t >> 5;              // 0..7
    const int wq = (t & 31) << 2;        // 0..124
    #pragma unroll
    for (int i = 0; i < 16; ++i) {
      const int ci = i * 8 + ciq;
      const float4 v = *(const float4*)(x + (((size_t)(b * 128 + ci) * 128 + h) * 128 + wq));
      tile[ci][wq] = v.x; tile[ci][wq + 1] = v.y;
      tile[ci][wq + 2] = v.z; tile[ci][wq + 3] = v.w;
    }
  }
  __syncthreads();
  {
    const int w = t & 127, p = t >> 7;
    float acc = 0.f;
    #pragma unroll 8
    for (int j = 0; j < 64; ++j) acc += tile[p * 64 + j][w];
    s2[p][w] = acc;
  }
  char* rowb = xt + (size_t)(b * 128 + h) * 32768;
  // granule u = (cih*8+q)*128 + w; store linear (coalesced); gather 8 ci
  #pragma unroll
  for (int i = 0; i < 8; ++i) {
    const int u = i * 256 + t;           // 0..2047 granule id
    const int w = u & 127;
    const int ci0 = (u >> 7) * 8;        // (cih*8+q)*8
    short8 o;
    #pragma unroll
    for (int j = 0; j < 8; ++j) o[j] = (short)f2b(tile[ci0 + j][w]);
    *(short8*)(rowb + (size_t)u * 16) = o;
  }
  __syncthreads();
  if (t < 128) s[(size_t)(b * 128 + h) * 128 + t] = s2[0][t] + s2[1][t];
}

// ---- conv: 4 waves; block 128co x 128w x 1h; 32x32x16 MFMA; 3 rows in LDS
__global__ __launch_bounds__(256, 3)
void conv_mfma_kernel(const char* __restrict__ xt, const char* __restrict__ wp,
                      const float* __restrict__ bias, const float* __restrict__ s,
                      float* __restrict__ out) {
  __shared__ uint4 xs4[3 * 1024];   // 48KB: 3 rows x [q:8][w:128][16B]
  char* xs = (char*)xs4;

  // bijective XCD swizzle: 4096 blocks, 8 XCDs, 512 contiguous per XCD.
  const int bid = blockIdx.x;
  const int sw = (bid & 7) * 512 + (bid >> 3);
  const int h = sw & 127;
  const int b = sw >> 7;

  const int t = threadIdx.x;
  const int lane = t & 63, wave = t >> 6;
  const int wm = wave >> 1, wn = wave & 1;
  const int l31 = lane & 31, kb = lane >> 5;

  f32x16 acc[2][2];
  #pragma unroll
  for (int mt = 0; mt < 2; ++mt)
    #pragma unroll
    for (int nt = 0; nt < 2; ++nt)
      #pragma unroll
      for (int r = 0; r < 16; ++r)
        acc[mt][nt][r] = 0.f;

  auto stage_x = [&](int cih) {
    #pragma unroll
    for (int r = 0; r < 3; ++r) {  // input rows h-1 .. h+1, zero-pad OOB
      const int hh = h - 1 + r;
      if ((unsigned)hh < 128u) {
        // linear 16KB copy: global [q][w] order == LDS order
        const char* rb = xt + ((size_t)(b * 128 + hh) * 32768 + cih * 16384);
        #pragma unroll
        for (int i = 0; i < 4; ++i) {
          const int u = i * 256 + t;   // 0..1023 granule
          gload_lds16(rb + (size_t)u * 16, xs + r * 16384 + u * 16);
        }
      } else {
        #pragma unroll
        for (int i = 0; i < 4; ++i) {
          const int u = i * 256 + t;
          *(uint4*)(xs + r * 16384 + u * 16) = make_uint4(0u, 0u, 0u, 0u);
        }
      }
    }
  };

  auto compute_half = [&](int cih) {
    #pragma unroll
    for (int kh = 0; kh < 3; ++kh) {
      const char* xrow = xs + kh * 16384;  // input row h-1+kh
      #pragma unroll
      for (int dxi = 0; dxi < 3; ++dxi) {
        const int tap = kh * 3 + dxi;
        const int dx = dxi - 1;
        // W base for this tap + ci-half; layout [tap][ks][kb][co][16B]
        const char* wb = wp + (size_t)((tap * 8 + cih * 4) * 2) * 2048;
        #pragma unroll
        for (int ks = 0; ks < 4; ++ks) {      // 4 k-steps of 16 per ci-half
          // A-fragments: 2 variants/block (wm) -> L1 broadcast.
          short8 af[2];
          #pragma unroll
          for (int mt = 0; mt < 2; ++mt)
            af[mt] = *(const short8*)(wb + (ks * 2 + kb) * 2048 +
                                      (wm * 64 + mt * 32 + l31) * 16);
          // B-fragments from LDS: addr = q*2048 + wsrc*16 -> stride-1 lanes,
          // conflict-free (no swizzle needed in ci-major layout)
          short8 bf[2];
          #pragma unroll
          for (int nt = 0; nt < 2; ++nt) {
            const int wsrc = wn * 64 + nt * 32 + l31 + dx;
            short8 v = {0, 0, 0, 0, 0, 0, 0, 0};
            if ((unsigned)wsrc < 128u)
              v = *(const short8*)(xrow + (ks * 2 + kb) * 2048 + wsrc * 16);
            bf[nt] = v;
          }
          #pragma unroll
          for (int mt = 0; mt < 2; ++mt)
            #pragma unroll
            for (int nt = 0; nt < 2; ++nt)
              acc[mt][nt] = __builtin_amdgcn_mfma_f32_32x32x16_bf16(
                  af[mt], bf[nt], acc[mt][nt], 0, 0, 0);
        }
      }
    }
  };

  stage_x(0);
  __syncthreads();                 // xs half-0 ready
  compute_half(0);
  __syncthreads();                 // all waves done reading xs half-0
  stage_x(1);
  __syncthreads();                 // xs half-1 ready
  compute_half(1);

  // epilogue: per-thread fp32 stencil from s (L3-resident) + bias (L2)
  const float* sb = s + (size_t)b * 16384;
  float dif[2];
  #pragma unroll
  for (int nt = 0; nt < 2; ++nt) {
    const int w = wn * 64 + nt * 32 + l31;
    const float sc = sb[h * 128 + w];
    const float up = sb[(h > 0 ? h - 1 : 0) * 128 + w];
    const float dn = sb[(h < 127 ? h + 1 : 127) * 128 + w];
    const float lf = sb[h * 128 + (w > 0 ? w - 1 : 0)];
    const float rt = sb[h * 128 + (w < 127 ? w + 1 : 127)];
    dif[nt] = up + dn + lf + rt - 4.0f * sc;
  }
  // 32x32 C/D layout (verified m74/m101): col=lane&31, row=(r&3)+8*(r>>2)+4*(lane>>5)
  #pragma unroll
  for (int mt = 0; mt < 2; ++mt) {
    #pragma unroll
    for (int r = 0; r < 16; ++r) {
      const int co = wm * 64 + mt * 32 + (r & 3) + 8 * (r >> 2) + 4 * kb;
      const float bv = bias[co];
      float* orow = out + ((size_t)(b * 128 + co) * 128 + h) * 128;
      #pragma unroll
      for (int nt = 0; nt < 2; ++nt) {
        const int w = wn * 64 + nt * 32 + l31;
        orow[w] = acc[mt][nt][r] + bv - THETA * dif[nt];
      }
    }
  }
}

extern "C" void kernel_launch(void* const* d_in, const int* in_sizes, int n_in,
                              void* d_out, int out_size, void* d_ws, size_t ws_size,
                              hipStream_t stream) {
  const float* x = (const float*)d_in[0];
  const float* W = (const float*)d_in[1];
  const float* bias = (const float*)d_in[2];
  float* out = (float*)d_out;
  char* ws = (char*)d_ws;
  char* xt = ws + XT_OFF;
  char* wp = ws + WP_OFF;
  float* s = (float*)(ws + S_OFF);
  // needs ~142,901,248 bytes of ws
  pack_w_kernel<<<dim3(128), dim3(128), 0, stream>>>(W, wp);
  transpose_sum_kernel<<<dim3(128, 32), dim3(256), 0, stream>>>(x, xt, s);
  conv_mfma_kernel<<<dim3(4096), dim3(256), 0, stream>>>(xt, wp, bias, s, out);
}

// Round 12
// 243.705 us; speedup vs baseline: 1.3121x; 1.1107x over previous
//
#include <hip/hip_runtime.h>
#include <hip/hip_bf16.h>

// CDC conv: out = conv3x3(x,W,zero-pad) + b - 0.7 * laplacian(channel_sum(x), edge-pad)
// fp8 e4m3 MFMA implicit GEMM (9 tap-GEMMs, K=Cin), fp32 stencil epilogue.
// Round 12: R11 diagnosis = operand-byte-bound (LDS b128 pipe at its 85 B/cyc
// ceiling AND af L1 path at same bytes). fp8 halves bytes on BOTH pipes at the
// same MFMA shape/rate (32x32x16_fp8_fp8). W scaled x16 into e4m3 normal range,
// epilogue x1/16; error budget ~0.3 << 3.36 threshold.
// fp8 X row = 16KB -> ALL 3 rows x full K fit in 48KB LDS -> single stage +
// single barrier per block (cih phases eliminated). Granules pack 2 k-steps
// per 16B so every b128 feeds 2 MFMAs: 72 ds_read_b128 + 72 global_b128/wave.
// Keep: (256,3) no-spill envelope, W block-broadcast, XCD swizzle, 32x32 C/D
// layout (m74/m101), 3 blocks/CU.
// ws: [0,64MB) x_t fp8 [b][h][kp:4][kb:2][w:128][16B], [128MB,+144KB) W_packed
// [tap][kp:4][kb:2][co:128][16B], then s[b][h][w] f32 (8MB).

typedef __attribute__((ext_vector_type(2))) long vlong2;
typedef __attribute__((ext_vector_type(16))) float f32x16;

#define THETA 0.7f
#define XT_OFF   0
#define WP_OFF   134217728ull
#define S_OFF    (134217728ull + 294912ull)

// f32 -> OCP e4m3fn, RNE (normal), saturate to 448, subnormal-correct.
__device__ __forceinline__ unsigned f2e4m3(float x) {
  unsigned u = __builtin_bit_cast(unsigned, x);
  unsigned s = (u >> 24) & 0x80u;
  unsigned au = u & 0x7FFFFFFFu;
  if (au >= 0x43E80000u) return s | 0x7Eu;        // |x| >= 464 -> 448
  if (au < 0x3C800000u) {                          // |x| < 2^-6 -> subnormal
    float q = __builtin_bit_cast(float, au) * 512.0f;   // / 2^-9
    return s | (unsigned)(int)(q + 0.5f);          // 0..8 (8 == min normal)
  }
  unsigned m = au + 0x000FFFFFu + ((au >> 20) & 1u);    // RNE at bit 20
  int e = (int)(m >> 23) - 127;
  unsigned mant = (m >> 20) & 7u;
  if (e > 8 || (e == 8 && mant == 7u)) return s | 0x7Eu;
  return s | ((unsigned)(e + 7) << 3) | mant;
}

__device__ __forceinline__ void gload_lds16(const void* g, void* l) {
  __builtin_amdgcn_global_load_lds(
      (const __attribute__((address_space(1))) unsigned int*)g,
      (__attribute__((address_space(3))) unsigned int*)l, 16, 0, 0);
}

// ---- pack W[co][ci][3][3] f32 -> wp[tap][kp:4][kb:2][co:128][16B] fp8 (x16)
// granule bytes: [0..7] = k=kp*32+kb*8+j (ks=2kp), [8..15] = k=kp*32+16+kb*8+j
__global__ void pack_w_kernel(const float* __restrict__ w, char* __restrict__ wp) {
  const int co = blockIdx.x, ci = threadIdx.x;
  const float* src = w + ((size_t)co * 128 + ci) * 9;
  const int kp = ci >> 5, r = ci & 31;
  const int half = (r >> 4) & 1, kb = (r >> 3) & 1, j = r & 7;
  #pragma unroll
  for (int tap = 0; tap < 9; ++tap) {
    const unsigned char bv = (unsigned char)f2e4m3(src[tap] * 16.0f);
    wp[(size_t)((tap * 4 + kp) * 2 + kb) * 2048 + co * 16 + half * 8 + j] = bv;
  }
}

// ---- x f32 -> x_t fp8 [b][h][kp:4][kb:2][w:128][16B] + s[b][h][w] = sum_ci x
__global__ __launch_bounds__(256)
void transpose_sum_kernel(const float* __restrict__ x, char* __restrict__ xt,
                          float* __restrict__ s) {
  __shared__ float tile[128][129];
  __shared__ float s2[2][128];
  const int h = blockIdx.x, b = blockIdx.y;
  const int t = threadIdx.x;
  {
    const int ciq = t >> 5;              // 0..7
    const int wq = (t & 31) << 2;        // 0..124
    #pragma unroll
    for (int i = 0; i < 16; ++i) {
      const int ci = i * 8 + ciq;
      const float4 v = *(const float4*)(x + (((size_t)(b * 128 + ci) * 128 + h) * 128 + wq));
      tile[ci][wq] = v.x; tile[ci][wq + 1] = v.y;
      tile[ci][wq + 2] = v.z; tile[ci][wq + 3] = v.w;
    }
  }
  __syncthreads();
  {
    const int w = t & 127, p = t >> 7;
    float acc = 0.f;
    #pragma unroll 8
    for (int j = 0; j < 64; ++j) acc += tile[p * 64 + j][w];
    s2[p][w] = acc;
  }
  char* rowb = xt + (size_t)(b * 128 + h) * 16384;
  // 1024 granules of 16B; granule u = (kp*2+kb)*128 + w
  #pragma unroll
  for (int i = 0; i < 4; ++i) {
    const int u = i * 256 + t;
    const int w = u & 127;
    const int kb = (u >> 7) & 1;
    const int kp = u >> 8;
    unsigned wd[4];
    #pragma unroll
    for (int half = 0; half < 2; ++half) {
      const int ci0 = kp * 32 + half * 16 + kb * 8;
      unsigned lo = 0, hi = 0;
      #pragma unroll
      for (int j = 0; j < 4; ++j) lo |= f2e4m3(tile[ci0 + j][w]) << (8 * j);
      #pragma unroll
      for (int j = 0; j < 4; ++j) hi |= f2e4m3(tile[ci0 + 4 + j][w]) << (8 * j);
      wd[half * 2] = lo; wd[half * 2 + 1] = hi;
    }
    *(uint4*)(rowb + (size_t)u * 16) = make_uint4(wd[0], wd[1], wd[2], wd[3]);
  }
  __syncthreads();
  if (t < 128) s[(size_t)(b * 128 + h) * 128 + t] = s2[0][t] + s2[1][t];
}

// ---- conv: 4 waves; block 128co x 128w x 1h; fp8 32x32x16; 1 stage, 1 barrier
__global__ __launch_bounds__(256, 3)
void conv_mfma_kernel(const char* __restrict__ xt, const char* __restrict__ wp,
                      const float* __restrict__ bias, const float* __restrict__ s,
                      float* __restrict__ out) {
  __shared__ uint4 xs4[3 * 1024];   // 48KB: 3 rows x [kp:4][kb:2][w:128][16B]
  char* xs = (char*)xs4;

  // bijective XCD swizzle: 4096 blocks, 8 XCDs, 512 contiguous per XCD.
  const int bid = blockIdx.x;
  const int sw = (bid & 7) * 512 + (bid >> 3);
  const int h = sw & 127;
  const int b = sw >> 7;

  const int t = threadIdx.x;
  const int lane = t & 63, wave = t >> 6;
  const int wm = wave >> 1, wn = wave & 1;
  const int l31 = lane & 31, kb = lane >> 5;

  f32x16 acc[2][2];
  #pragma unroll
  for (int mt = 0; mt < 2; ++mt)
    #pragma unroll
    for (int nt = 0; nt < 2; ++nt)
      #pragma unroll
      for (int r = 0; r < 16; ++r)
        acc[mt][nt][r] = 0.f;

  // stage all 3 input rows, full K (16KB each), linear copy
  #pragma unroll
  for (int r = 0; r < 3; ++r) {
    const int hh = h - 1 + r;
    if ((unsigned)hh < 128u) {
      const char* rb = xt + (size_t)(b * 128 + hh) * 16384;
      #pragma unroll
      for (int i = 0; i < 4; ++i) {
        const int u = i * 256 + t;
        gload_lds16(rb + (size_t)u * 16, xs + r * 16384 + u * 16);
      }
    } else {
      #pragma unroll
      for (int i = 0; i < 4; ++i) {
        const int u = i * 256 + t;
        *(uint4*)(xs + r * 16384 + u * 16) = make_uint4(0u, 0u, 0u, 0u);
      }
    }
  }
  __syncthreads();                 // the ONLY barrier

  #pragma unroll
  for (int kh = 0; kh < 3; ++kh) {
    const char* xrow = xs + kh * 16384;  // input row h-1+kh
    #pragma unroll
    for (int dxi = 0; dxi < 3; ++dxi) {
      const int tap = kh * 3 + dxi;
      const int dx = dxi - 1;
      const char* wb = wp + (size_t)(tap * 8) * 2048;  // [kp][kb] inside
      #pragma unroll
      for (int kp = 0; kp < 4; ++kp) {
        // A (W) fragments: 2 variants/block -> L1 broadcast; b128 = 2 k-steps
        vlong2 av[2];
        #pragma unroll
        for (int mt = 0; mt < 2; ++mt)
          av[mt] = *(const vlong2*)(wb + (kp * 2 + kb) * 2048 +
                                    (wm * 64 + mt * 32 + l31) * 16);
        // B (X) fragments from LDS: stride-16 dense, conflict-free
        vlong2 bv[2];
        #pragma unroll
        for (int nt = 0; nt < 2; ++nt) {
          const int wsrc = wn * 64 + nt * 32 + l31 + dx;
          vlong2 v; v[0] = 0; v[1] = 0;
          if ((unsigned)wsrc < 128u)
            v = *(const vlong2*)(xrow + (kp * 2 + kb) * 2048 + wsrc * 16);
          bv[nt] = v;
        }
        #pragma unroll
        for (int mt = 0; mt < 2; ++mt)
          #pragma unroll
          for (int nt = 0; nt < 2; ++nt) {
            acc[mt][nt] = __builtin_amdgcn_mfma_f32_32x32x16_fp8_fp8(
                av[mt][0], bv[nt][0], acc[mt][nt], 0, 0, 0);
            acc[mt][nt] = __builtin_amdgcn_mfma_f32_32x32x16_fp8_fp8(
                av[mt][1], bv[nt][1], acc[mt][nt], 0, 0, 0);
          }
      }
    }
  }

  // epilogue: per-thread fp32 stencil from s (L3-resident) + bias; undo W x16
  const float* sb = s + (size_t)b * 16384;
  float dif[2];
  #pragma unroll
  for (int nt = 0; nt < 2; ++nt) {
    const int w = wn * 64 + nt * 32 + l31;
    const float sc = sb[h * 128 + w];
    const float up = sb[(h > 0 ? h - 1 : 0) * 128 + w];
    const float dn = sb[(h < 127 ? h + 1 : 127) * 128 + w];
    const float lf = sb[h * 128 + (w > 0 ? w - 1 : 0)];
    const float rt = sb[h * 128 + (w < 127 ? w + 1 : 127)];
    dif[nt] = up + dn + lf + rt - 4.0f * sc;
  }
  // 32x32 C/D layout (m74/m101): col=lane&31, row=(r&3)+8*(r>>2)+4*(lane>>5)
  #pragma unroll
  for (int mt = 0; mt < 2; ++mt) {
    #pragma unroll
    for (int r = 0; r < 16; ++r) {
      const int co = wm * 64 + mt * 32 + (r & 3) + 8 * (r >> 2) + 4 * kb;
      const float bv = bias[co];
      float* orow = out + ((size_t)(b * 128 + co) * 128 + h) * 128;
      #pragma unroll
      for (int nt = 0; nt < 2; ++nt) {
        const int w = wn * 64 + nt * 32 + l31;
        orow[w] = acc[mt][nt][r] * 0.0625f + bv - THETA * dif[nt];
      }
    }
  }
}

extern "C" void kernel_launch(void* const* d_in, const int* in_sizes, int n_in,
                              void* d_out, int out_size, void* d_ws, size_t ws_size,
                              hipStream_t stream) {
  const float* x = (const float*)d_in[0];
  const float* W = (const float*)d_in[1];
  const float* bias = (const float*)d_in[2];
  float* out = (float*)d_out;
  char* ws = (char*)d_ws;
  char* xt = ws + XT_OFF;
  char* wp = ws + WP_OFF;
  float* s = (float*)(ws + S_OFF);
  pack_w_kernel<<<dim3(128), dim3(128), 0, stream>>>(W, wp);
  transpose_sum_kernel<<<dim3(128, 32), dim3(256), 0, stream>>>(x, xt, s);
  conv_mfma_kernel<<<dim3(4096), dim3(256), 0, stream>>>(xt, wp, bias, s, out);
}

// Round 13
// 216.938 us; speedup vs baseline: 1.4739x; 1.1234x over previous
//
#include <hip/hip_runtime.h>
#include <hip/hip_bf16.h>

// CDC conv: out = conv3x3(x,W,zero-pad) + b - 0.7 * laplacian(channel_sum(x), edge-pad)
// fp8 e4m3 MFMA implicit GEMM (9 tap-GEMMs, K=Cin), fp32 stencil epilogue.
// Round 13: (a) transpose uses HW v_cvt_pk_fp8_f32 (OCP on gfx950) instead of
// ~12-op branchy converter -> VALU cost of fp8 pack ~25x down; (b) conv LDS
// rows border-padded to 130 granules (zero at w=-1,128) -> bf ds_read is
// unconditional (72 exec-mask guards/wave deleted). LDS 49.9KB, still 3/CU.
// Keep R12: 32x32x16 fp8 MFMA, block 128co x 128w x 1h, 4 waves, (256,3),
// single stage + single barrier, W block-broadcast, XCD swizzle.
// ws: [0,64MB) x_t fp8 [b][h][kp:4][kb:2][w:128][16B], [128MB,+144KB) W_packed
// [tap][kp:4][kb:2][co:128][16B] (x16 scaled), then s[b][h][w] f32 (8MB).

typedef __attribute__((ext_vector_type(2))) long vlong2;
typedef __attribute__((ext_vector_type(16))) float f32x16;

#define THETA 0.7f
#define XT_OFF   0
#define WP_OFF   134217728ull
#define S_OFF    (134217728ull + 294912ull)

// f32 -> OCP e4m3fn, RNE (normal), saturate, subnormal-correct. (pack_w only)
__device__ __forceinline__ unsigned f2e4m3(float x) {
  unsigned u = __builtin_bit_cast(unsigned, x);
  unsigned s = (u >> 24) & 0x80u;
  unsigned au = u & 0x7FFFFFFFu;
  if (au >= 0x43E80000u) return s | 0x7Eu;        // |x| >= 464 -> 448
  if (au < 0x3C800000u) {                          // |x| < 2^-6 -> subnormal
    float q = __builtin_bit_cast(float, au) * 512.0f;   // / 2^-9
    return s | (unsigned)(int)(q + 0.5f);          // 0..8 (8 == min normal)
  }
  unsigned m = au + 0x000FFFFFu + ((au >> 20) & 1u);    // RNE at bit 20
  int e = (int)(m >> 23) - 127;
  unsigned mant = (m >> 20) & 7u;
  if (e > 8 || (e == 8 && mant == 7u)) return s | 0x7Eu;
  return s | ((unsigned)(e + 7) << 3) | mant;
}

__device__ __forceinline__ void gload_lds16(const void* g, void* l) {
  __builtin_amdgcn_global_load_lds(
      (const __attribute__((address_space(1))) unsigned int*)g,
      (__attribute__((address_space(3))) unsigned int*)l, 16, 0, 0);
}

// ---- pack W[co][ci][3][3] f32 -> wp[tap][kp:4][kb:2][co:128][16B] fp8 (x16)
// granule bytes: [0..7] = k=kp*32+kb*8+j (ks=2kp), [8..15] = k=kp*32+16+kb*8+j
__global__ void pack_w_kernel(const float* __restrict__ w, char* __restrict__ wp) {
  const int co = blockIdx.x, ci = threadIdx.x;
  const float* src = w + ((size_t)co * 128 + ci) * 9;
  const int kp = ci >> 5, r = ci & 31;
  const int half = (r >> 4) & 1, kb = (r >> 3) & 1, j = r & 7;
  #pragma unroll
  for (int tap = 0; tap < 9; ++tap) {
    const unsigned char bv = (unsigned char)f2e4m3(src[tap] * 16.0f);
    wp[(size_t)((tap * 4 + kp) * 2 + kb) * 2048 + co * 16 + half * 8 + j] = bv;
  }
}

// ---- x f32 -> x_t fp8 [b][h][kp:4][kb:2][w:128][16B] + s[b][h][w] = sum_ci x
__global__ __launch_bounds__(256)
void transpose_sum_kernel(const float* __restrict__ x, char* __restrict__ xt,
                          float* __restrict__ s) {
  __shared__ float tile[128][129];
  __shared__ float s2[2][128];
  const int h = blockIdx.x, b = blockIdx.y;
  const int t = threadIdx.x;
  {
    const int ciq = t >> 5;              // 0..7
    const int wq = (t & 31) << 2;        // 0..124
    #pragma unroll
    for (int i = 0; i < 16; ++i) {
      const int ci = i * 8 + ciq;
      const float4 v = *(const float4*)(x + (((size_t)(b * 128 + ci) * 128 + h) * 128 + wq));
      tile[ci][wq] = v.x; tile[ci][wq + 1] = v.y;
      tile[ci][wq + 2] = v.z; tile[ci][wq + 3] = v.w;
    }
  }
  __syncthreads();
  {
    const int w = t & 127, p = t >> 7;
    float acc = 0.f;
    #pragma unroll 8
    for (int j = 0; j < 64; ++j) acc += tile[p * 64 + j][w];
    s2[p][w] = acc;
  }
  char* rowb = xt + (size_t)(b * 128 + h) * 16384;
  // 1024 granules of 16B; granule u = (kp*2+kb)*128 + w; HW packed fp8 cvt
  #pragma unroll
  for (int i = 0; i < 4; ++i) {
    const int u = i * 256 + t;
    const int w = u & 127;
    const int kb = (u >> 7) & 1;
    const int kp = u >> 8;
    unsigned wd[4];
    #pragma unroll
    for (int half = 0; half < 2; ++half) {
      const int ci0 = kp * 32 + half * 16 + kb * 8;
      int lo = __builtin_amdgcn_cvt_pk_fp8_f32(tile[ci0 + 0][w], tile[ci0 + 1][w], 0, false);
      lo = __builtin_amdgcn_cvt_pk_fp8_f32(tile[ci0 + 2][w], tile[ci0 + 3][w], lo, true);
      int hi = __builtin_amdgcn_cvt_pk_fp8_f32(tile[ci0 + 4][w], tile[ci0 + 5][w], 0, false);
      hi = __builtin_amdgcn_cvt_pk_fp8_f32(tile[ci0 + 6][w], tile[ci0 + 7][w], hi, true);
      wd[half * 2] = (unsigned)lo; wd[half * 2 + 1] = (unsigned)hi;
    }
    *(uint4*)(rowb + (size_t)u * 16) = make_uint4(wd[0], wd[1], wd[2], wd[3]);
  }
  __syncthreads();
  if (t < 128) s[(size_t)(b * 128 + h) * 128 + t] = s2[0][t] + s2[1][t];
}

// ---- conv: 4 waves; block 128co x 128w x 1h; fp8 32x32x16; border-padded LDS
__global__ __launch_bounds__(256, 3)
void conv_mfma_kernel(const char* __restrict__ xt, const char* __restrict__ wp,
                      const float* __restrict__ bias, const float* __restrict__ s,
                      float* __restrict__ out) {
  // 3 rows x 8 kchunks x 130 granules x 16B = 49,920B; granule 0 and 129 of
  // each chunk are zero borders (w=-1 / w=128) -> unconditional bf reads.
  __shared__ uint4 xs4[3 * 8 * 130];
  char* xs = (char*)xs4;

  // bijective XCD swizzle: 4096 blocks, 8 XCDs, 512 contiguous per XCD.
  const int bid = blockIdx.x;
  const int sw = (bid & 7) * 512 + (bid >> 3);
  const int h = sw & 127;
  const int b = sw >> 7;

  const int t = threadIdx.x;
  const int lane = t & 63, wave = t >> 6;
  const int wm = wave >> 1, wn = wave & 1;
  const int l31 = lane & 31, kb = lane >> 5;

  f32x16 acc[2][2];
  #pragma unroll
  for (int mt = 0; mt < 2; ++mt)
    #pragma unroll
    for (int nt = 0; nt < 2; ++nt)
      #pragma unroll
      for (int r = 0; r < 16; ++r)
        acc[mt][nt][r] = 0.f;

  // zero borders: 3 rows x 8 chunks x 2 sides = 48 granules
  if (t < 48) {
    const int row = t >> 4, k = t & 15, chunk = k >> 1, side = k & 1;
    xs4[row * 1040 + chunk * 130 + side * 129] = make_uint4(0u, 0u, 0u, 0u);
  }
  // stage all 3 input rows (full K), linear global -> padded LDS
  #pragma unroll
  for (int r = 0; r < 3; ++r) {
    const int hh = h - 1 + r;
    if ((unsigned)hh < 128u) {
      const char* rb = xt + (size_t)(b * 128 + hh) * 16384;
      #pragma unroll
      for (int i = 0; i < 4; ++i) {
        const int u = i * 256 + t;          // 0..1023
        const int chunk = u >> 7, w = u & 127;
        gload_lds16(rb + (size_t)u * 16,
                    xs + (size_t)(r * 1040 + chunk * 130 + 1 + w) * 16);
      }
    } else {
      #pragma unroll
      for (int i = 0; i < 5; ++i) {
        const int u = i * 256 + t;
        if (u < 1040) xs4[r * 1040 + u] = make_uint4(0u, 0u, 0u, 0u);
      }
    }
  }
  __syncthreads();                 // the ONLY barrier

  #pragma unroll
  for (int kh = 0; kh < 3; ++kh) {
    const char* xrow = xs + kh * 16640;  // input row h-1+kh
    #pragma unroll
    for (int dxi = 0; dxi < 3; ++dxi) {
      const int tap = kh * 3 + dxi;
      const char* wb = wp + (size_t)(tap * 8) * 2048;  // [kp][kb] inside
      #pragma unroll
      for (int kp = 0; kp < 4; ++kp) {
        // A (W) fragments: 2 variants/block -> L1 broadcast; b128 = 2 k-steps
        vlong2 av[2];
        #pragma unroll
        for (int mt = 0; mt < 2; ++mt)
          av[mt] = *(const vlong2*)(wb + (kp * 2 + kb) * 2048 +
                                    (wm * 64 + mt * 32 + l31) * 16);
        // B (X) fragments from LDS: unconditional (borders are zero)
        vlong2 bv[2];
        #pragma unroll
        for (int nt = 0; nt < 2; ++nt)
          bv[nt] = *(const vlong2*)(xrow +
              (size_t)((kp * 2 + kb) * 130 + wn * 64 + nt * 32 + l31 + dxi) * 16);
        #pragma unroll
        for (int mt = 0; mt < 2; ++mt)
          #pragma unroll
          for (int nt = 0; nt < 2; ++nt) {
            acc[mt][nt] = __builtin_amdgcn_mfma_f32_32x32x16_fp8_fp8(
                av[mt][0], bv[nt][0], acc[mt][nt], 0, 0, 0);
            acc[mt][nt] = __builtin_amdgcn_mfma_f32_32x32x16_fp8_fp8(
                av[mt][1], bv[nt][1], acc[mt][nt], 0, 0, 0);
          }
      }
    }
  }

  // epilogue: per-thread fp32 stencil from s (L3-resident) + bias; undo W x16
  const float* sb = s + (size_t)b * 16384;
  float dif[2];
  #pragma unroll
  for (int nt = 0; nt < 2; ++nt) {
    const int w = wn * 64 + nt * 32 + l31;
    const float sc = sb[h * 128 + w];
    const float up = sb[(h > 0 ? h - 1 : 0) * 128 + w];
    const float dn = sb[(h < 127 ? h + 1 : 127) * 128 + w];
    const float lf = sb[h * 128 + (w > 0 ? w - 1 : 0)];
    const float rt = sb[h * 128 + (w < 127 ? w + 1 : 127)];
    dif[nt] = up + dn + lf + rt - 4.0f * sc;
  }
  // 32x32 C/D layout (m74/m101): col=lane&31, row=(r&3)+8*(r>>2)+4*(lane>>5)
  #pragma unroll
  for (int mt = 0; mt < 2; ++mt) {
    #pragma unroll
    for (int r = 0; r < 16; ++r) {
      const int co = wm * 64 + mt * 32 + (r & 3) + 8 * (r >> 2) + 4 * kb;
      const float bv = bias[co];
      float* orow = out + ((size_t)(b * 128 + co) * 128 + h) * 128;
      #pragma unroll
      for (int nt = 0; nt < 2; ++nt) {
        const int w = wn * 64 + nt * 32 + l31;
        orow[w] = acc[mt][nt][r] * 0.0625f + bv - THETA * dif[nt];
      }
    }
  }
}

extern "C" void kernel_launch(void* const* d_in, const int* in_sizes, int n_in,
                              void* d_out, int out_size, void* d_ws, size_t ws_size,
                              hipStream_t stream) {
  const float* x = (const float*)d_in[0];
  const float* W = (const float*)d_in[1];
  const float* bias = (const float*)d_in[2];
  float* out = (float*)d_out;
  char* ws = (char*)d_ws;
  char* xt = ws + XT_OFF;
  char* wp = ws + WP_OFF;
  float* s = (float*)(ws + S_OFF);
  pack_w_kernel<<<dim3(128), dim3(128), 0, stream>>>(W, wp);
  transpose_sum_kernel<<<dim3(128, 32), dim3(256), 0, stream>>>(x, xt, s);
  conv_mfma_kernel<<<dim3(4096), dim3(256), 0, stream>>>(xt, wp, bias, s, out);
}